// Round 1
// baseline (13092.960 us; speedup 1.0000x reference)
//
#include <hip/hip_runtime.h>

#define HW 17
#define NPIX (HW*HW)      // 289
#define PW 19             // 17 + 1-wide zero ring
#define FW 21             // 17 + 2-wide zero ring (scent conv)

__global__ __launch_bounds__(320)
void ca_kernel(const float* __restrict__ cell,
               const float* __restrict__ food,
               const float* __restrict__ w3,
               const float* __restrict__ b3,
               const float* __restrict__ w4,
               const float* __restrict__ b4,
               const int* __restrict__ steps_p,
               float* __restrict__ out_cell,
               float* __restrict__ out_food,
               float* __restrict__ out_cnt,
               float* __restrict__ out_abv)
{
    __shared__ float4 S[2][PW][PW];   // state: (c0,c1,c2,scent), zero ring
    __shared__ float  T[PW*PW];       // xn0 scratch for post-maxpool, zero ring
    __shared__ float  FS[FW*FW];      // food staging, zero ring (width 2)

    const int b  = blockIdx.x;
    const int tx = threadIdx.x;      // 0..16
    const int ty = threadIdx.y;      // 0..16
    const int tid = ty*HW + tx;      // 0..288

    // ---- zero-init padded LDS (borders must stay 0 forever) ----
    float* sflat = (float*)S;
    #pragma unroll
    for (int k = tid; k < 2*PW*PW*4; k += NPIX) sflat[k] = 0.f;
    for (int k = tid; k < PW*PW;     k += NPIX) T[k]  = 0.f;
    for (int k = tid; k < FW*FW;     k += NPIX) FS[k] = 0.f;
    __syncthreads();

    // ---- food: stage, and copy to output ----
    const float fv = food[b*NPIX + tid];
    out_food[b*NPIX + tid] = fv;
    FS[(ty+2)*FW + (tx+2)] = fv;
    __syncthreads();

    // ---- scent = 5x5 correlation (zero-pad 2) ----
    const float SK[5][5] = {
        {0.f,   0.125f, 0.25f, 0.125f, 0.f  },
        {0.125f,0.25f,  0.5f,  0.25f,  0.125f},
        {0.25f, 0.5f,   1.0f,  0.5f,   0.25f},
        {0.125f,0.25f,  0.5f,  0.25f,  0.125f},
        {0.f,   0.125f, 0.25f, 0.125f, 0.f  }};
    float scent = 0.f;
    #pragma unroll
    for (int r = 0; r < 5; ++r)
        #pragma unroll
        for (int c = 0; c < 5; ++c)
            if (!((r==0||r==4)&&(c==0||c==4)))   // compile-time folded zeros
                scent += SK[r][c] * FS[(ty+r)*FW + (tx+c)];

    // ---- initial state ----
    const int base = b*4*NPIX + tid;
    float ic0 = cell[base];
    float ic1 = cell[base +   NPIX];
    float ic2 = cell[base + 2*NPIX];
    S[0][ty+1][tx+1] = make_float4(ic0, ic1, ic2, scent);
    __syncthreads();

    const int steps = steps_p[0];
    // fallback (steps==0): reference returns input cell unchanged
    float fc0 = ic0, fc1 = ic1, fc2 = ic2, fc3 = cell[base + 3*NPIX];

    for (int s = 0; s < steps; ++s) {
        const int cur = s & 1, nxt = cur ^ 1;

        // 3x3 neighborhood of (c0,c1,c2,scent)
        float4 n00 = S[cur][ty  ][tx  ], n01 = S[cur][ty  ][tx+1], n02 = S[cur][ty  ][tx+2];
        float4 n10 = S[cur][ty+1][tx  ], n11 = S[cur][ty+1][tx+1], n12 = S[cur][ty+1][tx+2];
        float4 n20 = S[cur][ty+2][tx  ], n21 = S[cur][ty+2][tx+1], n22 = S[cur][ty+2][tx+2];

        // pre = maxpool3(x[:,0]) > 0.1 (zero ring equivalent to -inf pad under >0.1)
        float mx = fmaxf(fmaxf(fmaxf(n00.x,n01.x),fmaxf(n02.x,n10.x)),
                         fmaxf(fmaxf(n11.x,n12.x),fmaxf(n20.x,fmaxf(n21.x,n22.x))));
        const bool pre = mx > 0.1f;

        // y = [x(4), sobel_x(4), sobel_y(4)]
        float yv[12];
        #define SOBEL(comp, i) { \
            const float a00=n00.comp,a01=n01.comp,a02=n02.comp; \
            const float a10=n10.comp,a12=n12.comp; \
            const float a20=n20.comp,a21=n21.comp,a22=n22.comp; \
            yv[i]   = n11.comp; \
            yv[4+i] = ((a02-a00) + 2.f*(a12-a10) + (a22-a20)) * 0.125f; \
            yv[8+i] = ((a20-a00) + 2.f*(a21-a01) + (a22-a02)) * 0.125f; }
        SOBEL(x,0) SOBEL(y,1) SOBEL(z,2) SOBEL(w,3)
        #undef SOBEL

        // h = relu(W3 y + b3); d = W4 h + b4   (weights -> s_load/SGPR operands)
        float d0 = b4[0], d1 = b4[1], d2 = b4[2], d3 = b4[3];
        #pragma unroll
        for (int o = 0; o < 16; ++o) {
            float h = b3[o];
            #pragma unroll
            for (int c = 0; c < 12; ++c) h += w3[o*12+c] * yv[c];
            h = fmaxf(h, 0.f);
            d0 += w4[o]      * h;
            d1 += w4[16+o]   * h;
            d2 += w4[32+o]   * h;
            d3 += w4[48+o]   * h;
        }

        const float xn0 = n11.x + d0;
        const float xn1 = n11.y + d1;
        const float xn2 = n11.z + d2;
        const float xn3 = scent + d3;   // x ch3 == scent every step

        T[(ty+1)*PW + (tx+1)] = xn0;
        __syncthreads();

        // post = maxpool3(xn[:,0]) > 0.1
        const int t0 = ty*PW + tx;
        float px = fmaxf(fmaxf(fmaxf(T[t0],T[t0+1]),fmaxf(T[t0+2],T[t0+PW])),
                         fmaxf(fmaxf(T[t0+PW+1],T[t0+PW+2]),
                               fmaxf(T[t0+2*PW],fmaxf(T[t0+2*PW+1],T[t0+2*PW+2]))));
        const bool life = pre && (px > 0.1f);

        const float o0 = life ? fminf(fmaxf(xn0,-10.f),10.f) : 0.f;
        const float o1 = life ? fminf(fmaxf(xn1,-10.f),10.f) : 0.f;
        const float o2 = life ? fminf(fmaxf(xn2,-10.f),10.f) : 0.f;
        const float o3 = life ? fminf(fmaxf(xn3,-10.f),10.f) : 0.f;

        S[nxt][ty+1][tx+1] = make_float4(o0, o1, o2, scent);
        fc0 = o0; fc1 = o1; fc2 = o2; fc3 = o3;
        __syncthreads();
    }

    // ---- write final cell ----
    out_cell[base]          = fc0;
    out_cell[base +   NPIX] = fc1;
    out_cell[base + 2*NPIX] = fc2;
    out_cell[base + 3*NPIX] = fc3;

    // ---- block reduction: living_count (sum c0), living_above (count c0>0.1) ----
    T[tid]  = fc0;
    FS[tid] = (fc0 > 0.1f) ? 1.f : 0.f;
    __syncthreads();
    if (tid < HW) {
        float sum = 0.f, cnt = 0.f;
        #pragma unroll
        for (int k = 0; k < HW; ++k) { sum += T[tid*HW+k]; cnt += FS[tid*HW+k]; }
        T[300+tid] = sum; FS[400+tid] = cnt;
    }
    __syncthreads();
    if (tid == 0) {
        float sum = 0.f, cnt = 0.f;
        #pragma unroll
        for (int k = 0; k < HW; ++k) { sum += T[300+k]; cnt += FS[400+k]; }
        out_cnt[b] = sum;
        out_abv[b] = cnt;
    }
}

extern "C" void kernel_launch(void* const* d_in, const int* in_sizes, int n_in,
                              void* d_out, int out_size, void* d_ws, size_t ws_size,
                              hipStream_t stream) {
    const float* cell  = (const float*)d_in[0];
    const float* food  = (const float*)d_in[1];
    const float* w3    = (const float*)d_in[2];
    const float* b3    = (const float*)d_in[3];
    const float* w4    = (const float*)d_in[4];
    const float* b4    = (const float*)d_in[5];
    const int*   steps = (const int*)d_in[6];

    const int B = in_sizes[0] / (4*NPIX);

    float* out      = (float*)d_out;
    float* out_cell = out;
    float* out_food = out      + (size_t)B*4*NPIX;
    float* out_cnt  = out_food + (size_t)B*NPIX;
    float* out_abv  = out_cnt  + (size_t)B;

    dim3 blk(HW, HW);
    hipLaunchKernelGGL(ca_kernel, dim3(B), blk, 0, stream,
                       cell, food, w3, b3, w4, b4, steps,
                       out_cell, out_food, out_cnt, out_abv);
}

// Round 2
// 3221.153 us; speedup vs baseline: 4.0647x; 4.0647x over previous
//
#include <hip/hip_runtime.h>

#define HW 17
#define NPIX 289

__device__ __forceinline__ float bperm(int a, float v) {
    return __int_as_float(__builtin_amdgcn_ds_bpermute(a, __float_as_int(v)));
}
__device__ __forceinline__ float max3f(float a, float b, float c) { return fmaxf(fmaxf(a, b), c); }
__device__ __forceinline__ float clampf(float v) { return fminf(fmaxf(v, -10.f), 10.f); }

// One lane = one row (17 px) of one batch. 3 batches per wave (lanes 0..50),
// lanes 51..63 dead; lane 63 is the guaranteed-zero shuffle source for all
// out-of-range vertical neighbor reads (zero-pad == -inf pad under >0.1).
#define CA_CHUNK(C0, C1)                                                          \
{                                                                                 \
    constexpr int NC = (C1) - (C0);                                               \
    float sxl0[NC], sxl1[NC], sxl2[NC], syl0[NC], syl1[NC], syl2[NC];             \
    {                                                                             \
        float v[NC + 2], d[NC + 2];                                               \
        _Pragma("unroll")                                                         \
        for (int i = 0; i < NC + 2; ++i) {                                        \
            const int c = (C0) - 1 + i;                                           \
            float xv = (i == 0) ? pL0 : ((c >= HW) ? 0.f : x0[(c >= HW) ? 0 : c]);\
            float u = bperm(upA, xv), dd = bperm(dnA, xv);                        \
            v[i] = u + 2.f * xv + dd; d[i] = dd - u;                              \
        }                                                                         \
        _Pragma("unroll")                                                         \
        for (int j = 0; j < NC; ++j) {                                            \
            sxl0[j] = 0.125f * (v[j + 2] - v[j]);                                 \
            syl0[j] = 0.125f * (d[j] + 2.f * d[j + 1] + d[j + 2]);                \
        }                                                                         \
        _Pragma("unroll")                                                         \
        for (int i = 0; i < NC + 2; ++i) {                                        \
            const int c = (C0) - 1 + i;                                           \
            float xv = (i == 0) ? pL1 : ((c >= HW) ? 0.f : x1[(c >= HW) ? 0 : c]);\
            float u = bperm(upA, xv), dd = bperm(dnA, xv);                        \
            v[i] = u + 2.f * xv + dd; d[i] = dd - u;                              \
        }                                                                         \
        _Pragma("unroll")                                                         \
        for (int j = 0; j < NC; ++j) {                                            \
            sxl1[j] = 0.125f * (v[j + 2] - v[j]);                                 \
            syl1[j] = 0.125f * (d[j] + 2.f * d[j + 1] + d[j + 2]);                \
        }                                                                         \
        _Pragma("unroll")                                                         \
        for (int i = 0; i < NC + 2; ++i) {                                        \
            const int c = (C0) - 1 + i;                                           \
            float xv = (i == 0) ? pL2 : ((c >= HW) ? 0.f : x2[(c >= HW) ? 0 : c]);\
            float u = bperm(upA, xv), dd = bperm(dnA, xv);                        \
            v[i] = u + 2.f * xv + dd; d[i] = dd - u;                              \
        }                                                                         \
        _Pragma("unroll")                                                         \
        for (int j = 0; j < NC; ++j) {                                            \
            sxl2[j] = 0.125f * (v[j + 2] - v[j]);                                 \
            syl2[j] = 0.125f * (d[j] + 2.f * d[j + 1] + d[j + 2]);                \
        }                                                                         \
    }                                                                             \
    float dacc0[NC], dacc1[NC], dacc2[NC], dacc3[NC];                             \
    _Pragma("unroll")                                                             \
    for (int j = 0; j < NC; ++j) {                                                \
        dacc0[j] = b4[0]; dacc1[j] = b4[1]; dacc2[j] = b4[2]; dacc3[j] = b4[3];   \
    }                                                                             \
    _Pragma("clang loop unroll_count(2)")                                         \
    for (int o = 0; o < 16; ++o) {                                                \
        const float wx0 = w3[o*12+0], wx1 = w3[o*12+1], wx2 = w3[o*12+2], wx3 = w3[o*12+3]; \
        const float wa0 = w3[o*12+4], wa1 = w3[o*12+5], wa2 = w3[o*12+6], wa3 = w3[o*12+7]; \
        const float wb0 = w3[o*12+8], wb1 = w3[o*12+9], wb2 = w3[o*12+10], wb3 = w3[o*12+11];\
        const float bo = b3[o];                                                   \
        const float u0 = w4[o], u1 = w4[16+o], u2 = w4[32+o], u3 = w4[48+o];      \
        _Pragma("unroll")                                                         \
        for (int j = 0; j < NC; ++j) {                                            \
            const int c = (C0) + j;                                               \
            float h = bo;                                                         \
            h += wx0 * x0[c]; h += wx1 * x1[c]; h += wx2 * x2[c]; h += wx3 * sc[c]; \
            h += wa0 * sxl0[j]; h += wa1 * sxl1[j]; h += wa2 * sxl2[j]; h += wa3 * sx3[c]; \
            h += wb0 * syl0[j]; h += wb1 * syl1[j]; h += wb2 * syl2[j]; h += wb3 * sy3[c]; \
            h = fmaxf(h, 0.f);                                                    \
            dacc0[j] += u0 * h; dacc1[j] += u1 * h; dacc2[j] += u2 * h; dacc3[j] += u3 * h; \
        }                                                                         \
    }                                                                             \
    pL0 = x0[(C1) - 1]; pL1 = x1[(C1) - 1]; pL2 = x2[(C1) - 1];                   \
    _Pragma("unroll")                                                             \
    for (int j = 0; j < NC; ++j) {                                                \
        const int c = (C0) + j;                                                   \
        x0[c] = (x0[c] + dacc0[j]) * am;                                          \
        x1[c] = (x1[c] + dacc1[j]) * am;                                          \
        x2[c] = (x2[c] + dacc2[j]) * am;                                          \
        x3o[c] = (sc[c] + dacc3[j]) * am;                                         \
    }                                                                             \
}

__global__ __launch_bounds__(256)
void ca_kernel(const float* __restrict__ cell, const float* __restrict__ food,
               const float* __restrict__ w3, const float* __restrict__ b3,
               const float* __restrict__ w4, const float* __restrict__ b4,
               const int* __restrict__ steps_p, const int B,
               float* __restrict__ out_cell, float* __restrict__ out_food,
               float* __restrict__ out_cnt, float* __restrict__ out_abv)
{
    const int t    = threadIdx.x;
    const int lane = t & 63;
    const int wid  = blockIdx.x * (blockDim.x >> 6) + (t >> 6);
    const int bl   = lane / 17;                // 0..2 real, 3 dead
    const int r    = lane - bl * 17;
    const int batch = wid * 3 + bl;
    const bool active = (bl < 3) && (batch < B);
    const float am = active ? 1.f : 0.f;

    // vertical-neighbor shuffle addresses; out-of-range -> lane 63 (always zero)
    const int upA  = ((r >= 1)             ? (lane - 1) : 63) << 2;
    const int dnA  = ((r <= 15 && bl < 3)  ? (lane + 1) : 63) << 2;
    const int up2A = ((r >= 2)             ? (lane - 2) : 63) << 2;
    const int dn2A = ((r <= 14 && bl < 3)  ? (lane + 2) : 63) << 2;

    // ---- food load + copy-out ----
    const size_t fbase = (size_t)(active ? batch : 0) * NPIX + (size_t)r * HW;
    float f[HW];
    #pragma unroll
    for (int c = 0; c < HW; ++c) f[c] = active ? food[fbase + c] : 0.f;
    #pragma unroll
    for (int c = 0; c < HW; ++c) if (active) out_food[fbase + c] = f[c];

    // ---- scent: separable 5x5 [.25,.5,1,.5,.25]^2 minus .0625*corners ----
    float hf[HW];
    #pragma unroll
    for (int c = 0; c < HW; ++c) {
        float s = f[c];
        if (c >= 1)  s += 0.5f  * f[c - 1];
        if (c <= 15) s += 0.5f  * f[c + 1];
        if (c >= 2)  s += 0.25f * f[c - 2];
        if (c <= 14) s += 0.25f * f[c + 2];
        hf[c] = s;
    }
    float sc[HW];
    {
        float fu2[HW], fd2[HW];
        #pragma unroll
        for (int c = 0; c < HW; ++c) {
            float u1 = bperm(upA, hf[c]),  d1 = bperm(dnA, hf[c]);
            float u2 = bperm(up2A, hf[c]), d2 = bperm(dn2A, hf[c]);
            sc[c] = hf[c] + 0.5f * (u1 + d1) + 0.25f * (u2 + d2);
            fu2[c] = bperm(up2A, f[c]);
            fd2[c] = bperm(dn2A, f[c]);
        }
        #pragma unroll
        for (int c = 0; c < HW; ++c) {
            float corr = 0.f;
            if (c >= 2)  corr += fu2[c - 2] + fd2[c - 2];
            if (c <= 14) corr += fu2[c + 2] + fd2[c + 2];
            sc[c] = (sc[c] - 0.0625f * corr) * am;   // dead lanes exactly 0
        }
    }

    // ---- scent-channel sobel (constant across steps) ----
    float sx3[HW], sy3[HW];
    {
        float vS[HW + 2], dS[HW + 2];
        vS[0] = 0.f; vS[HW + 1] = 0.f; dS[0] = 0.f; dS[HW + 1] = 0.f;
        #pragma unroll
        for (int c = 0; c < HW; ++c) {
            float u = bperm(upA, sc[c]), d = bperm(dnA, sc[c]);
            vS[c + 1] = u + 2.f * sc[c] + d;
            dS[c + 1] = d - u;
        }
        #pragma unroll
        for (int c = 0; c < HW; ++c) {
            sx3[c] = 0.125f * (vS[c + 2] - vS[c]);
            sy3[c] = 0.125f * (dS[c] + 2.f * dS[c + 1] + dS[c + 2]);
        }
    }

    // ---- initial state ----
    const size_t cb = (size_t)(active ? batch : 0) * (4 * NPIX) + (size_t)r * HW;
    float x0[HW], x1[HW], x2[HW], x3o[HW];
    #pragma unroll
    for (int c = 0; c < HW; ++c) {
        x0[c]  = active ? cell[cb + c] : 0.f;
        x1[c]  = active ? cell[cb + NPIX + c] : 0.f;
        x2[c]  = active ? cell[cb + 2 * NPIX + c] : 0.f;
        x3o[c] = active ? cell[cb + 3 * NPIX + c] : 0.f;
    }

    const int steps = steps_p[0];
    for (int s = 0; s < steps; ++s) {
        // ---- pre maxpool on ch0 ----
        float premax[HW];
        {
            float rm[HW];
            #pragma unroll
            for (int c = 0; c < HW; ++c) {
                float a = (c >= 1) ? x0[c - 1] : 0.f;
                float cc = (c <= 15) ? x0[c + 1] : 0.f;
                rm[c] = max3f(a, x0[c], cc);
            }
            #pragma unroll
            for (int c = 0; c < HW; ++c)
                premax[c] = max3f(rm[c], bperm(upA, rm[c]), bperm(dnA, rm[c]));
        }

        float pL0 = 0.f, pL1 = 0.f, pL2 = 0.f;   // old left-halo col stash
        CA_CHUNK(0, 6)
        CA_CHUNK(6, 12)
        CA_CHUNK(12, 17)

        // ---- post maxpool on ungated xn0 + life gate ----
        {
            float rm[HW];
            #pragma unroll
            for (int c = 0; c < HW; ++c) {
                float a = (c >= 1) ? x0[c - 1] : 0.f;
                float cc = (c <= 15) ? x0[c + 1] : 0.f;
                rm[c] = max3f(a, x0[c], cc);     // dead lanes: x0 masked 0
            }
            #pragma unroll
            for (int c = 0; c < HW; ++c) {
                float pm = max3f(rm[c], bperm(upA, rm[c]), bperm(dnA, rm[c]));
                const bool L = (premax[c] > 0.1f) && (pm > 0.1f);
                x0[c]  = L ? clampf(x0[c])  : 0.f;
                x1[c]  = L ? clampf(x1[c])  : 0.f;
                x2[c]  = L ? clampf(x2[c])  : 0.f;
                x3o[c] = L ? clampf(x3o[c]) : 0.f;
            }
        }
    }

    // ---- final outputs ----
    #pragma unroll
    for (int c = 0; c < HW; ++c) {
        if (active) {
            out_cell[cb + c]            = x0[c];
            out_cell[cb + NPIX + c]     = x1[c];
            out_cell[cb + 2 * NPIX + c] = x2[c];
            out_cell[cb + 3 * NPIX + c] = x3o[c];
        }
    }
    float rs = 0.f, rc = 0.f;
    #pragma unroll
    for (int c = 0; c < HW; ++c) {
        rs += x0[c];
        rc += (x0[c] > 0.1f) ? 1.f : 0.f;
    }
    float ssum = rs, scnt = rc;
    for (int k = 1; k <= 16; ++k) {
        int a = ((lane + k) & 63) << 2;
        ssum += bperm(a, rs);
        scnt += bperm(a, rc);
    }
    if (active && r == 0) { out_cnt[batch] = ssum; out_abv[batch] = scnt; }
}

extern "C" void kernel_launch(void* const* d_in, const int* in_sizes, int n_in,
                              void* d_out, int out_size, void* d_ws, size_t ws_size,
                              hipStream_t stream) {
    const float* cell  = (const float*)d_in[0];
    const float* food  = (const float*)d_in[1];
    const float* w3    = (const float*)d_in[2];
    const float* b3    = (const float*)d_in[3];
    const float* w4    = (const float*)d_in[4];
    const float* b4    = (const float*)d_in[5];
    const int*   steps = (const int*)d_in[6];

    const int B = in_sizes[0] / (4 * NPIX);

    float* out      = (float*)d_out;
    float* out_cell = out;
    float* out_food = out      + (size_t)B * 4 * NPIX;
    float* out_cnt  = out_food + (size_t)B * NPIX;
    float* out_abv  = out_cnt  + (size_t)B;

    const int waves  = (B + 2) / 3;
    const int blocks = (waves + 3) / 4;
    hipLaunchKernelGGL(ca_kernel, dim3(blocks), dim3(256), 0, stream,
                       cell, food, w3, b3, w4, b4, steps, B,
                       out_cell, out_food, out_cnt, out_abv);
}